// Round 3
// baseline (157.648 us; speedup 1.0000x reference)
//
#include <hip/hip_runtime.h>
#include <hip/hip_bf16.h>

#define NB 8
#define BIN 512
#define BOUT 512
#define BATCH 8192
#define DIM 4096   // NB*BIN

typedef __attribute__((ext_vector_type(8))) short bf16x8;
typedef __attribute__((ext_vector_type(4))) float f32x4;

#define SWZ(r) (((r) & 7) << 4)

__device__ __forceinline__ unsigned short f2bf_rne(float f) {
    unsigned u = __builtin_bit_cast(unsigned, f);
    unsigned r = (u + 0x7FFFu + ((u >> 16) & 1u)) >> 16;
    return (unsigned short)r;
}

// ---------------- weight conversion: f32 -> bf16 ----------------
__global__ void cvt_f32_bf16(const float* __restrict__ in,
                             unsigned short* __restrict__ out, int n4) {
    int i = blockIdx.x * blockDim.x + threadIdx.x;
    if (i >= n4) return;
    f32x4 v = *(const f32x4*)(in + (size_t)i * 4);
    unsigned long long p =  (unsigned long long)f2bf_rne(v.x)
        | ((unsigned long long)f2bf_rne(v.y) << 16)
        | ((unsigned long long)f2bf_rne(v.z) << 32)
        | ((unsigned long long)f2bf_rne(v.w) << 48);
    *(unsigned long long*)(out + (size_t)i * 4) = p;
}

// ---------------- fused 2-layer block-diag MLP ----------------
// One workgroup: 64 batch rows x one full diagonal block (512 cols), both layers.
// 256 threads = 4 waves (1x4 over cols). Per wave: 64 rows x 128 cols (4x8 frags).
// W1/W2 fragments are read DIRECTLY from L2 (no LDS staging for weights).
// LDS: As[64][64] bf16 (x tile, f32->bf16) + Hs[64][512] bf16 = 72 KB -> 2 blocks/CU.
__global__ __launch_bounds__(256, 2)
void fused_mlp(const float* __restrict__ X,
               const unsigned short* __restrict__ W1,
               const float* __restrict__ B1,
               const unsigned short* __restrict__ W2,
               const float* __restrict__ B2,
               float* __restrict__ Out)
{
    __shared__ __align__(16) unsigned char As[64 * 128];    // [64][64] bf16 swizzled, 8 KB
    __shared__ __align__(16) unsigned char Hs[64 * 1024];   // [64][512] bf16 swizzled, 64 KB

    const int bid = blockIdx.x;
    // XCD pin: default dispatch round-robins XCDs (d%8), so nb = bid&7 keeps each
    // diagonal block's weights resident in one XCD's L2.
    const int nb = bid & 7;
    const int mt = bid >> 3;      // 0..127

    const int t = threadIdx.x;
    const int lane = t & 63;
    const int wn = t >> 6;        // wave 0..3 -> col range wn*128..+128
    const int l15 = lane & 15;
    const int lhi = lane >> 4;    // 0..3

    const int row0 = mt * 64;     // batch-row base
    const int wc0  = nb * 512;    // block base in the 4096-wide dims

    // staging geometry: thread t covers row r = t>>2, cols c4..c4+15 (f32)
    const int sr = t >> 2;
    const int sc = (t & 3) * 16;

    f32x4 acc[4][8];
    #pragma unroll
    for (int m = 0; m < 4; m++)
        #pragma unroll
        for (int n = 0; n < 8; n++)
            acc[m][n] = (f32x4)(0.f);

    // ---- prologue: prefetch kt=0 x-slice into regs ----
    f32x4 xp[4];
    #pragma unroll
    for (int j = 0; j < 4; j++)
        xp[j] = *(const f32x4*)(X + (size_t)(row0 + sr) * DIM + wc0 + sc + j * 4);

    // ================= phase 1: h = relu(x @ W1^T + b1) =================
    for (int kt = 0; kt < BIN; kt += 64) {
        if (kt) __syncthreads();          // all waves done reading As(prev)
        // convert xp -> bf16, write As
        #pragma unroll
        for (int h = 0; h < 2; h++) {
            bf16x8 v;
            #pragma unroll
            for (int j = 0; j < 2; j++) {
                f32x4 f = xp[h * 2 + j];
                v[j * 4 + 0] = (short)f2bf_rne(f.x);
                v[j * 4 + 1] = (short)f2bf_rne(f.y);
                v[j * 4 + 2] = (short)f2bf_rne(f.z);
                v[j * 4 + 3] = (short)f2bf_rne(f.w);
            }
            *(bf16x8*)(As + sr * 128 + (((sc + 8 * h) * 2) ^ SWZ(sr))) = v;
        }
        // prefetch next kt (hides under barrier + MFMA section)
        if (kt < BIN - 64) {
            #pragma unroll
            for (int j = 0; j < 4; j++)
                xp[j] = *(const f32x4*)(X + (size_t)(row0 + sr) * DIM + wc0 + (kt + 64) + sc + j * 4);
        }
        __syncthreads();                  // As ready

        #pragma unroll
        for (int ks = 0; ks < 2; ks++) {
            const int k0 = ks * 32 + lhi * 8;
            bf16x8 af[4], bfr[8];
            #pragma unroll
            for (int m = 0; m < 4; m++) {
                int r = m * 16 + l15;
                af[m] = *(const bf16x8*)(As + r * 128 + ((k0 * 2) ^ SWZ(r)));
            }
            #pragma unroll
            for (int n = 0; n < 8; n++) {
                int wr = wc0 + wn * 128 + n * 16 + l15;
                bfr[n] = *(const bf16x8*)(W1 + (size_t)wr * BIN + kt + k0);
            }
            #pragma unroll
            for (int m = 0; m < 4; m++)
                #pragma unroll
                for (int n = 0; n < 8; n++)
                    acc[m][n] = __builtin_amdgcn_mfma_f32_16x16x32_bf16(
                        af[m], bfr[n], acc[m][n], 0, 0, 0);
        }
    }

    // write h = relu(acc + b1) into Hs [64][512] bf16 (own cols; no barrier needed yet)
    #pragma unroll
    for (int n = 0; n < 8; n++) {
        int c = wn * 128 + n * 16 + l15;          // local h col (= layer-2 k)
        float bv = B1[wc0 + c];
        #pragma unroll
        for (int m = 0; m < 4; m++) {
            int rb = m * 16 + lhi * 4;
            #pragma unroll
            for (int rr = 0; rr < 4; rr++) {
                float v = acc[m][n][rr] + bv;
                v = v > 0.f ? v : 0.f;
                int r = rb + rr;
                *(unsigned short*)(Hs + r * 1024 + ((c * 2) ^ SWZ(r))) = f2bf_rne(v);
            }
        }
    }
    __syncthreads();

    #pragma unroll
    for (int m = 0; m < 4; m++)
        #pragma unroll
        for (int n = 0; n < 8; n++)
            acc[m][n] = (f32x4)(0.f);

    // ================= phase 2: out = relu(h @ W2^T + b2) =================
    // No barriers: h frags from LDS, W2 frags direct from L2.
    #pragma unroll 2
    for (int ks = 0; ks < 16; ks++) {
        const int k0 = ks * 32 + lhi * 8;
        bf16x8 af[4], bfr[8];
        #pragma unroll
        for (int m = 0; m < 4; m++) {
            int r = m * 16 + l15;
            af[m] = *(const bf16x8*)(Hs + r * 1024 + ((k0 * 2) ^ SWZ(r)));
        }
        #pragma unroll
        for (int n = 0; n < 8; n++) {
            int wr = wc0 + wn * 128 + n * 16 + l15;
            bfr[n] = *(const bf16x8*)(W2 + (size_t)wr * BIN + k0);
        }
        #pragma unroll
        for (int m = 0; m < 4; m++)
            #pragma unroll
            for (int n = 0; n < 8; n++)
                acc[m][n] = __builtin_amdgcn_mfma_f32_16x16x32_bf16(
                    af[m], bfr[n], acc[m][n], 0, 0, 0);
    }

    // epilogue: out = relu(acc + b2), f32
    #pragma unroll
    for (int n = 0; n < 8; n++) {
        int c = wc0 + wn * 128 + n * 16 + l15;
        float bv = B2[c];
        #pragma unroll
        for (int m = 0; m < 4; m++) {
            int rb = row0 + m * 16 + lhi * 4;
            #pragma unroll
            for (int rr = 0; rr < 4; rr++) {
                float v = acc[m][n][rr] + bv;
                Out[(size_t)(rb + rr) * DIM + c] = v > 0.f ? v : 0.f;
            }
        }
    }
}

extern "C" void kernel_launch(void* const* d_in, const int* in_sizes, int n_in,
                              void* d_out, int out_size, void* d_ws, size_t ws_size,
                              hipStream_t stream) {
    const float* x  = (const float*)d_in[0];
    const float* W1 = (const float*)d_in[1];
    const float* b1 = (const float*)d_in[2];
    const float* W2 = (const float*)d_in[3];
    const float* b2 = (const float*)d_in[4];
    float* out = (float*)d_out;

    char* ws = (char*)d_ws;
    unsigned short* W1bf = (unsigned short*)ws;                    // 4 MB
    unsigned short* W2bf = (unsigned short*)(ws + (4u << 20));     // 4 MB

    const int WELEM = NB * BOUT * BIN;          // 2,097,152 per weight tensor
    cvt_f32_bf16<<<(WELEM / 4 + 255) / 256, 256, 0, stream>>>(W1, W1bf, WELEM / 4);
    cvt_f32_bf16<<<(WELEM / 4 + 255) / 256, 256, 0, stream>>>(W2, W2bf, WELEM / 4);

    const int GRID = NB * (BATCH / 64);         // 8 * 128 = 1024
    fused_mlp<<<GRID, 256, 0, stream>>>(x, W1bf, b1, W2bf, b2, out);
}

// Round 4
// 99.910 us; speedup vs baseline: 1.5779x; 1.5779x over previous
//
#include <hip/hip_runtime.h>
#include <hip/hip_bf16.h>

#define NB 8
#define BIN 512
#define BOUT 512
#define BATCH 8192
#define DIM 4096   // NB*BIN

typedef __attribute__((ext_vector_type(8))) short bf16x8;
typedef __attribute__((ext_vector_type(4))) float f32x4;

#define SWZ(r) (((r) & 7) << 4)

__device__ __forceinline__ unsigned short f2bf_rne(float f) {
    unsigned u = __builtin_bit_cast(unsigned, f);
    unsigned r = (u + 0x7FFFu + ((u >> 16) & 1u)) >> 16;
    return (unsigned short)r;
}

__device__ __forceinline__ unsigned long long pack4(f32x4 f) {
    return (unsigned long long)f2bf_rne(f.x)
         | ((unsigned long long)f2bf_rne(f.y) << 16)
         | ((unsigned long long)f2bf_rne(f.z) << 32)
         | ((unsigned long long)f2bf_rne(f.w) << 48);
}

// ---------------- weight pack: f32 [nb][512][512] -> per-(nb,wn) bf16 fragment streams ----------------
// Stream layout: frag (nb, wn, kidx 0..15, n 0..7): 64 lanes x 16B, contiguous 1KB.
// In-kernel fragment load: stream + ((kidx*8+n)*512 + lane*8) ushorts.
__global__ void pack_w(const float* __restrict__ W, unsigned short* __restrict__ pk) {
    int gid = blockIdx.x * 256 + threadIdx.x;        // 262144 total
    int lane = gid & 63;
    int n    = (gid >> 6) & 7;
    int kidx = (gid >> 9) & 15;
    int wn   = (gid >> 13) & 3;
    int nb   = gid >> 15;
    int row  = wn * 128 + n * 16 + (lane & 15);      // 0..511 within block
    int col  = kidx * 32 + (lane >> 4) * 8;          // 0..511
    const float* s = W + ((size_t)nb * BOUT + row) * BIN + col;
    f32x4 a = *(const f32x4*)s;
    f32x4 b = *(const f32x4*)(s + 4);
    unsigned long long* d = (unsigned long long*)(pk + (size_t)gid * 8);
    d[0] = pack4(a);
    d[1] = pack4(b);
}

// ---------------- fused 2-layer block-diag MLP ----------------
// wg: 128 batch rows x one full diagonal block (512 cols), both layers.
// 512 threads = 8 waves, 2(M) x 4(N); per wave 64x128 out = 4x8 fp32x4 acc.
// W never touches LDS: register-double-buffered fragment-stream loads (q0/q1).
// As (x tile) double-buffered in LDS, ONE raw barrier per K-step, counted waits
// (lgkmcnt(0) only) so global prefetch stays in flight across barriers.
__global__ __launch_bounds__(512, 2)
void fused_mlp(const float* __restrict__ X,
               const unsigned short* __restrict__ PK1,
               const float* __restrict__ B1,
               const unsigned short* __restrict__ PK2,
               const float* __restrict__ B2,
               float* __restrict__ Out)
{
    __shared__ __align__(16) unsigned char pool[131072];
    unsigned char* As = pool;                 // [2][128 rows][128B] = 32 KB (phase 1)
    unsigned char* Hs = pool;                 // [128 rows][1024B] = 128 KB (phase 2, reuses pool)

    const int bid = blockIdx.x;
    const int nb = bid & 7;       // XCD pin: keeps this block's W streams in one L2
    const int mt = bid >> 3;      // 0..63

    const int t = threadIdx.x;
    const int lane = t & 63;
    const int wid = t >> 6;
    const int wm = wid >> 2;      // 0..1
    const int wn = wid & 3;       // 0..3
    const int l15 = lane & 15;
    const int lhi = lane >> 4;

    const int row0 = mt * 128;
    const int wc0  = nb * 512;

    const int sr = t >> 2;        // staging row 0..127
    const int sc = (t & 3) * 16;  // staging col (f32) 0,16,32,48

    const unsigned short* s1 = PK1 + (size_t)(nb * 4 + wn) * 65536;
    const unsigned short* s2 = PK2 + (size_t)(nb * 4 + wn) * 65536;

    f32x4 acc[4][8];
    #pragma unroll
    for (int m = 0; m < 4; m++)
        #pragma unroll
        for (int n = 0; n < 8; n++)
            acc[m][n] = (f32x4)(0.f);

    f32x4 xp[4];
    bf16x8 q0[8], q1[8];

#define LOAD_XP(KT) { \
    _Pragma("unroll") for (int j = 0; j < 4; j++) \
        xp[j] = *(const f32x4*)(X + (size_t)(row0 + sr) * DIM + wc0 + (KT) * 64 + sc + j * 4); }

#define STAGE_AS(BUF) { \
    _Pragma("unroll") for (int h2 = 0; h2 < 2; h2++) { \
        bf16x8 v; \
        ((unsigned long long*)&v)[0] = pack4(xp[h2 * 2 + 0]); \
        ((unsigned long long*)&v)[1] = pack4(xp[h2 * 2 + 1]); \
        *(bf16x8*)(As + (BUF) * 16384 + sr * 128 + (((sc + 8 * h2) * 2) ^ SWZ(sr))) = v; } }

#define LOADQ(Q, S, KIDX) { \
    _Pragma("unroll") for (int n = 0; n < 8; n++) \
        Q[n] = *(const bf16x8*)((S) + ((KIDX) * 8 + n) * 512 + lane * 8); }

#define MFMA32(Q, AF) \
    __builtin_amdgcn_s_setprio(1); \
    _Pragma("unroll") for (int m = 0; m < 4; m++) \
        _Pragma("unroll") for (int n = 0; n < 8; n++) \
            acc[m][n] = __builtin_amdgcn_mfma_f32_16x16x32_bf16(AF[m], Q[n], acc[m][n], 0, 0, 0); \
    __builtin_amdgcn_s_setprio(0);

#define P1STEP(Q, BUF, KS) { \
    bf16x8 af[4]; \
    const int cb_ = ((KS) * 32 + lhi * 8) * 2; \
    _Pragma("unroll") for (int m = 0; m < 4; m++) { \
        const int r_ = wm * 64 + m * 16 + l15; \
        af[m] = *(const bf16x8*)(As + (BUF) * 16384 + r_ * 128 + (cb_ ^ SWZ(r_))); } \
    MFMA32(Q, af) }

#define P2STEP(Q, KIDX) { \
    bf16x8 af[4]; \
    const int cb_ = ((KIDX) * 32 + lhi * 8) * 2; \
    _Pragma("unroll") for (int m = 0; m < 4; m++) { \
        const int r_ = wm * 64 + m * 16 + l15; \
        af[m] = *(const bf16x8*)(Hs + r_ * 1024 + (cb_ ^ SWZ(r_))); } \
    MFMA32(Q, af) }

#define BAR() { \
    asm volatile("s_waitcnt lgkmcnt(0)" ::: "memory"); \
    __builtin_amdgcn_s_barrier(); \
    __builtin_amdgcn_sched_barrier(0); }

    // ---- prologue ----
    LOAD_XP(0);
    STAGE_AS(0);
    LOAD_XP(1);
    LOADQ(q0, s1, 0);
    BAR();

    // ================= phase 1: h = relu(x @ W1^T + b1) =================
    #pragma unroll
    for (int kt = 0; kt < 8; kt++) {
        const int buf = kt & 1;
        LOADQ(q1, s1, 2 * kt + 1);          // prefetch next W1 frag set
        P1STEP(q0, buf, 0);
        if (kt < 7) { STAGE_AS(buf ^ 1); }  // stage x tile for kt+1 (other buffer)
        if (kt < 6) { LOAD_XP(kt + 2); }    // prefetch x for kt+2
        if (kt < 7) { LOADQ(q0, s1, 2 * kt + 2); }
        else        { LOADQ(q0, s2, 0); }   // seed phase-2 W2 prefetch
        P1STEP(q1, buf, 1);
        BAR();                              // writes visible; global loads stay in flight
    }

    // ---- h = relu(acc + b1) -> Hs (pool reuse; kt=7 BAR guaranteed As reads done) ----
    #pragma unroll
    for (int n = 0; n < 8; n++) {
        const int c = wn * 128 + n * 16 + l15;
        const float bv = B1[wc0 + c];
        #pragma unroll
        for (int m = 0; m < 4; m++) {
            #pragma unroll
            for (int rr = 0; rr < 4; rr++) {
                float v = acc[m][n][rr] + bv;
                v = v > 0.f ? v : 0.f;
                const int r = wm * 64 + m * 16 + lhi * 4 + rr;
                *(unsigned short*)(Hs + r * 1024 + ((c * 2) ^ SWZ(r))) = f2bf_rne(v);
            }
        }
    }
    BAR();

    #pragma unroll
    for (int m = 0; m < 4; m++)
        #pragma unroll
        for (int n = 0; n < 8; n++)
            acc[m][n] = (f32x4)(0.f);

    // ================= phase 2: out = relu(h @ W2^T + b2), no barriers =================
    #pragma unroll
    for (int kk = 0; kk < 8; kk++) {
        LOADQ(q1, s2, 2 * kk + 1);
        P2STEP(q0, 2 * kk);
        if (kk < 7) { LOADQ(q0, s2, 2 * kk + 2); }
        P2STEP(q1, 2 * kk + 1);
    }

    // ---- epilogue: out = relu(acc + b2), f32 ----
    #pragma unroll
    for (int n = 0; n < 8; n++) {
        const int c = wc0 + wn * 128 + n * 16 + l15;
        const float bv = B2[c];
        #pragma unroll
        for (int m = 0; m < 4; m++) {
            const int rb = row0 + wm * 64 + m * 16 + lhi * 4;
            #pragma unroll
            for (int rr = 0; rr < 4; rr++) {
                float v = acc[m][n][rr] + bv;
                Out[(size_t)(rb + rr) * DIM + c] = v > 0.f ? v : 0.f;
            }
        }
    }

#undef LOAD_XP
#undef STAGE_AS
#undef LOADQ
#undef MFMA32
#undef P1STEP
#undef P2STEP
#undef BAR
}

extern "C" void kernel_launch(void* const* d_in, const int* in_sizes, int n_in,
                              void* d_out, int out_size, void* d_ws, size_t ws_size,
                              hipStream_t stream) {
    const float* x  = (const float*)d_in[0];
    const float* W1 = (const float*)d_in[1];
    const float* b1 = (const float*)d_in[2];
    const float* W2 = (const float*)d_in[3];
    const float* b2 = (const float*)d_in[4];
    float* out = (float*)d_out;

    char* ws = (char*)d_ws;
    unsigned short* PK1 = (unsigned short*)ws;                 // 4 MB
    unsigned short* PK2 = (unsigned short*)(ws + (4u << 20));  // 4 MB

    pack_w<<<1024, 256, 0, stream>>>(W1, PK1);
    pack_w<<<1024, 256, 0, stream>>>(W2, PK2);

    const int GRID = NB * (BATCH / 128);    // 512
    fused_mlp<<<GRID, 512, 0, stream>>>(x, PK1, b1, PK2, b2, out);
}